// Round 2
// baseline (1374.725 us; speedup 1.0000x reference)
//
#include <hip/hip_runtime.h>

// SpectralConv1d: out[pos,o,k] = sum_i x[pos,i,k] * w[o,i,k]  (complex, per-mode k)
// x: (16384, 32, 64, 2) f32; w: (32, 32, 64, 2) f32; out: (16384, 32, 64, 2) f32.
//
// R2 design: block = 8 positions x all 32 o. x tile staged to LDS ONCE via
// global_load_lds (16B), double-buffered over 4 i-chunks of 8. Lane owns a
// k-pair (float4 = 2 complex modes). 16 groups = 8 og (4 o) x 2 pg (4 pos).
// Eliminates the R1 8x redundant x reads from L3 (~2.1 GB -> 268 MB).

constexpr int D_IN  = 32;
constexpr int D_OUT = 32;
constexpr int KP    = 32;          // k-pairs (float4 = 2 complex modes)
constexpr int NPOS  = 8 * 2048;
constexpr int POSB  = 8;           // positions per block
constexpr int IC    = 8;           // i per staged chunk
constexpr int NC    = D_IN / IC;   // 4 chunks
constexpr int PT    = 4;           // positions per thread
constexpr int OT    = 4;           // outputs per thread
constexpr int THREADS = 512;

__global__ __launch_bounds__(THREADS, 4)
void spectral_conv1d_kernel(const float4* __restrict__ x,
                            const float4* __restrict__ w,
                            float4* __restrict__ out) {
    // 2 x 32 KB double buffer: [buf][pos][ii][kp]
    __shared__ float4 lbuf[2][POSB * IC * KP];

    const int tid  = threadIdx.x;
    const int kp   = tid & 31;
    const int grp  = tid >> 5;          // 0..15
    const int og   = grp & 7;           // 8 o-groups
    const int pg   = grp >> 3;          // 2 pos-groups
    const int o0   = og * OT;
    const int p0   = pg * PT;
    const int wave = tid >> 6;          // 0..7 -> staging position
    const int lane = tid & 63;
    const long posBase = (long)blockIdx.x * POSB;

    // Staging source: pos (posBase+wave); each i-row is 512 B, chunk = 4 KB contiguous.
    const char* xrow = (const char*)x
                     + ((posBase + wave) * D_IN) * (KP * (long)sizeof(float4))
                     + lane * 16;

    auto stage = [&](int c) {
        const char* src = xrow + (size_t)c * IC * KP * sizeof(float4);   // +c*4096
        char* dstBase = (char*)&lbuf[c & 1][wave * (IC * KP)];           // wave-uniform
        #pragma unroll
        for (int j = 0; j < 4; ++j) {
            __builtin_amdgcn_global_load_lds(
                (const __attribute__((address_space(1))) unsigned int*)(src + j * 1024),
                (__attribute__((address_space(3))) unsigned int*)(dstBase + j * 1024),
                16, 0, 0);
        }
    };

    const float4* wb = w + (long)o0 * D_IN * KP + kp;

    float4 acc[PT][OT];
    #pragma unroll
    for (int p = 0; p < PT; ++p)
        #pragma unroll
        for (int j = 0; j < OT; ++j) acc[p][j] = make_float4(0.f, 0.f, 0.f, 0.f);

    stage(0);
    __syncthreads();

    for (int c = 0; c < NC; ++c) {
        if (c + 1 < NC) stage(c + 1);   // async into other buffer; drained by barrier below
        const float4* xb = &lbuf[c & 1][0];
        #pragma unroll
        for (int ii = 0; ii < IC; ++ii) {
            const int i = c * IC + ii;
            float4 wv[OT];
            #pragma unroll
            for (int j = 0; j < OT; ++j)
                wv[j] = wb[(j * D_IN + i) * KP];          // L1-hot 16 KB/i slice
            float4 xv[PT];
            #pragma unroll
            for (int p = 0; p < PT; ++p)
                xv[p] = xb[((p0 + p) * IC + ii) * KP + kp];
            #pragma unroll
            for (int p = 0; p < PT; ++p)
                #pragma unroll
                for (int j = 0; j < OT; ++j) {
                    acc[p][j].x = fmaf(xv[p].x,  wv[j].x, acc[p][j].x);
                    acc[p][j].x = fmaf(-xv[p].y, wv[j].y, acc[p][j].x);
                    acc[p][j].y = fmaf(xv[p].x,  wv[j].y, acc[p][j].y);
                    acc[p][j].y = fmaf(xv[p].y,  wv[j].x, acc[p][j].y);
                    acc[p][j].z = fmaf(xv[p].z,  wv[j].z, acc[p][j].z);
                    acc[p][j].z = fmaf(-xv[p].w, wv[j].w, acc[p][j].z);
                    acc[p][j].w = fmaf(xv[p].z,  wv[j].w, acc[p][j].w);
                    acc[p][j].w = fmaf(xv[p].w,  wv[j].z, acc[p][j].w);
                }
        }
        __syncthreads();
    }

    float4* ob = out + (posBase + p0) * D_OUT * KP + kp;
    #pragma unroll
    for (int p = 0; p < PT; ++p)
        #pragma unroll
        for (int j = 0; j < OT; ++j)
            ob[((long)p * D_OUT + o0 + j) * KP] = acc[p][j];
}

extern "C" void kernel_launch(void* const* d_in, const int* in_sizes, int n_in,
                              void* d_out, int out_size, void* d_ws, size_t ws_size,
                              hipStream_t stream) {
    const float4* x = (const float4*)d_in[0];
    const float4* w = (const float4*)d_in[1];
    float4* out     = (float4*)d_out;

    dim3 grid(NPOS / POSB);   // 2048 blocks
    spectral_conv1d_kernel<<<grid, THREADS, 0, stream>>>(x, w, out);
}